// Round 4
// baseline (9787.663 us; speedup 1.0000x reference)
//
#include <hip/hip_runtime.h>
#include <math.h>

// Problem constants (fixed by reference setup_inputs)
#define RS 3072   // B*CH signals
#define NF 2048   // signal length N
#define MS 512    // measurements M
#define NBLK 512  // persistent grid: 2 blocks/CU on 256 CUs (co-resident)

typedef _Float16 f16;
typedef _Float16 f16x4 __attribute__((ext_vector_type(4)));
typedef _Float16 f16x8 __attribute__((ext_vector_type(8)));
typedef float f32x4 __attribute__((ext_vector_type(4)));

// idxs may be int64 (pairs [lo,0]) or int32; sorted-unique => idxs[1] >= 1.
__device__ __forceinline__ int load_idx(const int* p, int j) {
    return (p[1] == 0) ? p[2 * j] : p[j];
}

#define PI_OVER_4096 7.669903939428206e-4f
#define CK0 0.022097086912079608f  // sqrt(1/2048)
#define CKN 0.03125f               // sqrt(2/2048)

__device__ __forceinline__ void async_copy16(const void* g, void* l) {
    __builtin_amdgcn_global_load_lds(
        (__attribute__((address_space(1))) const void*)g,
        (__attribute__((address_space(3))) void*)l, 16, 0, 0);
}

// H = clamp(20*(v+c), -1, 1) in f16 — single definition shared by phase-1
// staging and phase-2 epilogue so both round identically (round-2 numerics).
__device__ __forceinline__ f16 hclamp(f16 v, f16 c) {
    f16 s = (f16)((v + c) * (f16)20.0);
    s = s > (f16)1.0 ? (f16)1.0 : s;
    s = s < (f16)-1.0 ? (f16)-1.0 : s;
    return s;
}

// Grid barrier: monotone arrival counter (no reset races) + epoch flag.
// Agent-scope atomics reach the device coherence point (cross-XCD safe);
// release fence writes back L2 before arrival, acquire fence invalidates
// after release so post-barrier reads see other XCDs' writes.
__device__ __forceinline__ void gbar(int* cnt, int* flag, int ep) {
    __syncthreads();
    if (threadIdx.x == 0) {
        __builtin_amdgcn_fence(__ATOMIC_RELEASE, "agent");
        int old = __hip_atomic_fetch_add(cnt, 1, __ATOMIC_RELAXED,
                                         __HIP_MEMORY_SCOPE_AGENT);
        if (old == ep * NBLK - 1) {
            __hip_atomic_store(flag, ep, __ATOMIC_RELAXED,
                               __HIP_MEMORY_SCOPE_AGENT);
        } else {
            while (__hip_atomic_load(flag, __ATOMIC_RELAXED,
                                     __HIP_MEMORY_SCOPE_AGENT) < ep)
                __builtin_amdgcn_s_sleep(2);
        }
        __builtin_amdgcn_fence(__ATOMIC_ACQUIRE, "agent");
    }
    __syncthreads();
}

// One output tile: acc[u][r] = sum_k A[u][k]*B[r][k]; A async-staged; B async
// (or virtual H computed from v,c when MODE==1). u = output-contiguous dim.
// MODE 0: c = 100*acc; v = 0                       (A=Wh, B=Bm)
// MODE 1: Y = acc                                  (A=Wg, B=H(v,c) virtual)
// MODE 2: v += 0.05*(acc - H(v,c))                 (A=Wh, B=Y)
// MODE 3: MODE2 then store F' = g - 0.05*clip(20g), g = v_new + c
// MODE 4: out = 0.01*acc (f32)                     (A=Dg, B=F')
template<int BU, int BR, int MODE>
__device__ void tile_gemm(int bu, int br,
    const f16* __restrict__ A, const f16* __restrict__ B,
    const f16* __restrict__ vb, const f16* __restrict__ cb,
    f16* __restrict__ o16, f16* __restrict__ o16b, float* __restrict__ outF,
    int K, int ldo, f16* As, f16* Bs)
{
    constexpr int WU = BU / 2, WR = BR / 2;
    constexpr int IM = WU / 16, IN = WR / 16;
    const int tid = threadIdx.x;
    const int w = tid >> 6, l = tid & 63;
    const int wr = w >> 1, wc = w & 1;
    const int q = l >> 4, ln = l & 15;
    const int lrow = l >> 2, lk8 = (l & 3) * 8;

    f32x4 acc[IM][IN];
#pragma unroll
    for (int a = 0; a < IM; ++a)
#pragma unroll
        for (int b = 0; b < IN; ++b)
            acc[a][b] = (f32x4){0.f, 0.f, 0.f, 0.f};

    const f16* Ab = A + (size_t)bu * K + lk8;
    const f16* Bb = (MODE == 1) ? (const f16*)nullptr : B + (size_t)br * K + lk8;

    for (int k0 = 0; k0 < K; k0 += 32) {
#pragma unroll
        for (int i = 0; i < BU / 64; ++i)
            async_copy16(Ab + (size_t)(i * 64 + w * 16 + lrow) * K + k0,
                         As + i * 2048 + w * 512 + l * 8);
        if constexpr (MODE == 1) {
            // virtual B: 64 rows x 32 k, 8 f16/thread, clamp on the fly
            const int row = tid >> 2, kk = (tid & 3) * 8;
            const size_t go = (size_t)(br + row) * NF + k0 + kk;
            f16x8 vg = *(const f16x8*)(vb + go);
            f16x8 cg = *(const f16x8*)(cb + go);
            f16x8 z;
#pragma unroll
            for (int e = 0; e < 8; ++e) z[e] = hclamp(vg[e], cg[e]);
            *(f16x8*)(Bs + row * 32 + kk) = z;
        } else {
#pragma unroll
            for (int i = 0; i < BR / 64; ++i)
                async_copy16(Bb + (size_t)(i * 64 + w * 16 + lrow) * K + k0,
                             Bs + i * 2048 + w * 512 + l * 8);
        }
        __syncthreads();

        f16x8 af[IM], bf[IN];
#pragma unroll
        for (int im = 0; im < IM; ++im)
            af[im] = *(const f16x8*)(As + (wr * WU + im * 16 + ln) * 32 + q * 8);
#pragma unroll
        for (int in = 0; in < IN; ++in)
            bf[in] = *(const f16x8*)(Bs + (wc * WR + in * 16 + ln) * 32 + q * 8);
#pragma unroll
        for (int im = 0; im < IM; ++im)
#pragma unroll
            for (int in = 0; in < IN; ++in)
                acc[im][in] = __builtin_amdgcn_mfma_f32_16x16x32_f16(
                    af[im], bf[in], acc[im][in], 0, 0, 0);
        __syncthreads();
    }

    // epilogue: C/D layout col(lane&15)=r-frag, row(q*4+reg)=u-frag (contig)
#pragma unroll
    for (int im = 0; im < IM; ++im) {
#pragma unroll
        for (int in = 0; in < IN; ++in) {
            const int u0 = bu + wr * WU + im * 16 + q * 4;
            const int r0 = br + wc * WR + in * 16 + ln;
            const size_t off = (size_t)r0 * ldo + u0;
            f32x4 a4 = acc[im][in];
            if constexpr (MODE == 0) {
                f16x4 cc, zz;
#pragma unroll
                for (int e = 0; e < 4; ++e) { cc[e] = (f16)(100.0f * a4[e]); zz[e] = (f16)0.0; }
                *(f16x4*)(o16 + off) = cc;
                *(f16x4*)(o16b + off) = zz;
            } else if constexpr (MODE == 1) {
                f16x4 yy;
#pragma unroll
                for (int e = 0; e < 4; ++e) yy[e] = (f16)a4[e];
                *(f16x4*)(o16 + off) = yy;
            } else if constexpr (MODE == 2 || MODE == 3) {
                f16x4 v4 = *(const f16x4*)(vb + off);
                f16x4 c4 = *(const f16x4*)(cb + off);
                f16x4 st;
#pragma unroll
                for (int e = 0; e < 4; ++e) {
                    f16 hz = hclamp(v4[e], c4[e]);            // == phase-1 operand
                    float vn = (float)v4[e] + 0.05f * (a4[e] - (float)hz);
                    if constexpr (MODE == 2) {
                        st[e] = (f16)vn;
                    } else {
                        float g = vn + (float)c4[e];          // fold c: F' = g - 0.05*h100
                        float zf = fminf(fmaxf(20.0f * g, -1.f), 1.f);
                        st[e] = (f16)(g - 0.05f * zf);
                    }
                }
                *(f16x4*)(o16 + off) = st;
            } else {
                f32x4 ov;
#pragma unroll
                for (int e = 0; e < 4; ++e) ov[e] = 0.01f * a4[e];
                *(f32x4*)(outF + off) = ov;
            }
        }
    }
}

__global__ __launch_bounds__(256, 2) void solver(
    const float* __restrict__ x, const int* __restrict__ idxs,
    f16* Wg, f16* Wh, f16* BmY, f16* c16, f16* v16, f16* Dg,
    float* __restrict__ outF, int* bar)
{
    __shared__ __align__(16) f16 As[128 * 32];
    __shared__ __align__(16) f16 Bs[128 * 32];
    const int blk = blockIdx.x;
    const int xcd = blk & 7, local = blk >> 3;   // XCD-major block decode
    const int gtid = blk * 256 + threadIdx.x;
    int* cnt = bar;
    int* flag = bar + 32;   // separate cacheline
    int ep = 0;

    // ---- Phase A: build Wg [j][k], Wh [n][j], Bm [r][j]
    for (int t = gtid; t < MS * NF; t += NBLK * 256) {
        int j = t >> 11, k = t & (NF - 1);
        int ii = load_idx(idxs, j);
        float ck = (k == 0) ? CK0 : CKN;
        int phv = ((2 * ii + 1) * k) & 8191;
        float v = ck * cosf((float)phv * PI_OVER_4096);
        Wg[(size_t)j * NF + k] = (f16)v;
        Wh[(size_t)k * MS + j] = (f16)v;
    }
    for (int t = gtid; t < RS * MS; t += NBLK * 256) {
        int r = t >> 9, j = t & (MS - 1);
        BmY[t] = (f16)(x[(size_t)r * NF + load_idx(idxs, j)]);
    }
    gbar(cnt, flag, ++ep);

    // ---- Phase B: c = 100*Bm@A (384 tiles 128x128; XCD owns 3 r-panels)
    if (local < 48) {
        int up = local & 15, rp = xcd * 3 + (local >> 4);
        tile_gemm<128, 128, 0>(up * 128, rp * 128, Wh, BmY, nullptr, nullptr,
                               c16, v16, nullptr, MS, NF, As, Bs);
    }
    gbar(cnt, flag, ++ep);

    // ---- 99 iterations
    for (int it = 0; it < 99; ++it) {
        // Phase 1: Y = Wg @ H(v,c)  (384 tiles 64x64; XCD owns 6 r-panels)
        if (local < 48) {
            int up = local & 7, rp = xcd * 6 + (local >> 3);
            tile_gemm<64, 64, 1>(up * 64, rp * 64, Wg, nullptr, v16, c16,
                                 BmY, nullptr, nullptr, NF, MS, As, Bs);
        }
        gbar(cnt, flag, ++ep);
        // Phase 2: v += 0.05*(Wh@Y - H)  (384 tiles 128x128)
        if (local < 48) {
            int up = local & 15, rp = xcd * 3 + (local >> 4);
            if (it < 98)
                tile_gemm<128, 128, 2>(up * 128, rp * 128, Wh, BmY, v16, c16,
                                       v16, nullptr, nullptr, MS, NF, As, Bs);
            else
                tile_gemm<128, 128, 3>(up * 128, rp * 128, Wh, BmY, v16, c16,
                                       v16, nullptr, nullptr, MS, NF, As, Bs);
        }
        gbar(cnt, flag, ++ep);
    }

    // ---- Phase D: build Dg [i][k] (overwrites Wg/Wh/Bm/c-head — all dead)
    for (int t = gtid; t < NF * NF; t += NBLK * 256) {
        int i = t >> 11, k = t & (NF - 1);
        float ck = (k == 0) ? CK0 : CKN;
        int phv = ((2 * i + 1) * k) & 8191;
        Dg[(size_t)i * NF + k] = (f16)(ck * cosf((float)phv * PI_OVER_4096));
    }
    gbar(cnt, flag, ++ep);

    // ---- Phase E: out = 0.01 * F' @ D  (384 tiles; XCD owns 2 Dg u-panels)
    if (local < 48) {
        int up = xcd * 2 + (local & 1), rp = local >> 1;
        tile_gemm<128, 128, 4>(up * 128, rp * 128, Dg, v16, nullptr, nullptr,
                               nullptr, nullptr, outF, NF, NF, As, Bs);
    }
}

extern "C" void kernel_launch(void* const* d_in, const int* in_sizes, int n_in,
                              void* d_out, int out_size, void* d_ws, size_t ws_size,
                              hipStream_t stream) {
    const float* x = (const float*)d_in[0];
    const int* idxs = (const int*)d_in[1];

    // Workspace: identical envelope to round-2's proven layout (~32.8 MB).
    // Dg (8 MB) aliases Wg|Wh|BmY|c16[0:1.05MB) — all dead before Phase D.
    char* p = (char*)d_ws;
    auto take = [&](size_t n) { char* q = p; p += (n + 255) & ~(size_t)255; return q; };
    f16* Wg  = (f16*)take((size_t)MS * NF * 2);   // 2 MB
    f16* Wh  = (f16*)take((size_t)NF * MS * 2);   // 2 MB
    f16* BmY = (f16*)take((size_t)RS * MS * 2);   // 3 MB   Bm, then Y
    f16* c16 = (f16*)take((size_t)RS * NF * 2);   // 12.6 MB
    f16* v16 = (f16*)take((size_t)RS * NF * 2);   // 12.6 MB  v, then F'
    int* bar = (int*)take(256);                   // barrier state
    f16* Dg  = (f16*)d_ws;                        // aliased idct matrix

    hipMemsetAsync(bar, 0, 256, stream);
    solver<<<dim3(NBLK), 256, 0, stream>>>(
        x, idxs, Wg, Wh, BmY, c16, v16, Dg, (float*)d_out, bar);
}

// Round 5
// 5289.175 us; speedup vs baseline: 1.8505x; 1.8505x over previous
//
#include <hip/hip_runtime.h>
#include <math.h>

// Problem constants (fixed by reference setup_inputs)
#define RS 3072   // B*CH signals
#define NF 2048   // signal length N
#define MS 512    // measurements M

typedef _Float16 f16;
typedef _Float16 f16x4 __attribute__((ext_vector_type(4)));
typedef _Float16 f16x8 __attribute__((ext_vector_type(8)));
typedef float f32x4 __attribute__((ext_vector_type(4)));

// idxs may be int64 (pairs [lo,0]) or int32; sorted-unique => idxs[1] >= 1.
__device__ __forceinline__ int load_idx(const int* p, int j) {
    return (p[1] == 0) ? p[2 * j] : p[j];
}

#define PI_OVER_4096 7.669903939428206e-4f
#define CK0 0.022097086912079608f  // sqrt(1/2048)
#define CKN 0.03125f               // sqrt(2/2048)

// Wg[j][k] = A[j,k] (512x2048, k-contig);  Wh[n][j] = A[j,n] (2048x512, j-contig)
__global__ void build_w_kernel(const int* idxs, f16* Wg, f16* Wh) {
    int t = blockIdx.x * 256 + threadIdx.x;   // over MS*NF
    int j = t >> 11, k = t & (NF - 1);
    int ii = load_idx(idxs, j);
    float ck = (k == 0) ? CK0 : CKN;
    int ph = ((2 * ii + 1) * k) & 8191;
    float v = ck * cosf((float)ph * PI_OVER_4096);
    Wg[(size_t)j * NF + k] = (f16)v;
    Wh[(size_t)k * MS + j] = (f16)v;
}

// Dg[i][k] = IDCT[i,k] = c_k cos(pi*(2i+1)k/4096)  (2048x2048, k-contig)
__global__ void build_d_kernel(f16* Dg) {
    int t = blockIdx.x * 256 + threadIdx.x;   // over NF*NF
    int i = t >> 11, k = t & (NF - 1);
    float ck = (k == 0) ? CK0 : CKN;
    int ph = ((2 * i + 1) * k) & 8191;
    Dg[(size_t)i * NF + k] = (f16)(ck * cosf((float)ph * PI_OVER_4096));
}

// Bm[r][j] = x[r, idxs[j]]  (UNSCALED; c = 100*acc in epilogue)
__global__ void build_b_kernel(const float* x, const int* idxs, f16* Bm) {
    int t = blockIdx.x * 256 + threadIdx.x;   // over RS*MS
    int r = t >> 9, j = t & (MS - 1);
    Bm[t] = (f16)(x[(size_t)r * NF + load_idx(idxs, j)]);
}

// H = clamp(20*(v+c), -1, 1) in f16 — single definition shared by phase-1
// staging and phase-2 epilogue so both round identically (round-2 numerics).
__device__ __forceinline__ f16 hclamp(f16 v, f16 c) {
    f16 s = (f16)((v + c) * (f16)20.0);
    s = s > (f16)1.0 ? (f16)1.0 : s;
    s = s < (f16)-1.0 ? (f16)-1.0 : s;
    return s;
}

// Pipelined GEMM: acc[u][r] = sum_k A[u][k]*B[r][k].
// 1-deep global->VGPR prefetch + double-buffered LDS: stage s+1's global
// loads are in flight while stage s computes from LDS; compiler's vmcnt(0)
// lands before the ds_write (after compute), not in a dead pre-barrier drain.
// LDS rows padded to BK+8 elems (stride 144B, bank-rotating => <=2-way, free).
// MODE 0: c = 100*acc; v = 0              (A=Wh, B=Bm)
// MODE 1: Y = acc                         (A=Wg, B=H(v,c) clamped in regs)
// MODE 2: v += 0.05*(acc - H(v,c))        (A=Wh, B=Y)
// MODE 3: MODE2 then store F' = g - 0.05*clip(20g), g = v_new + c
// MODE 4: out = 0.01*acc (f32)            (A=Dg, B=F')
template<int BU, int BR, int BK, int KT, int NP, int RPX, int LNP, int GRP, int MODE>
__global__ __launch_bounds__(256) void gemm_p(
    const f16* __restrict__ A, const f16* __restrict__ B,
    const f16* __restrict__ vb, const f16* __restrict__ cb,
    f16* __restrict__ o16, f16* __restrict__ o16b,
    float* __restrict__ outF, int ldo)
{
    constexpr int WU = BU / 2, WR = BR / 2;       // 4 waves, 2x2
    constexpr int IM = WU / 16, IN = WR / 16;
    constexpr int SA = BK + 8;                    // padded LDS row stride
    constexpr int CPR = BK / 8;                   // f16x8 chunks per row
    constexpr int RPP = 256 / CPR;                // rows staged per pass
    constexpr int PA = BU / RPP, PB = BR / RPP;
    constexpr int NS = KT / BK;                   // pipeline stages

    __shared__ __align__(16) f16 As[2 * BU * SA];
    __shared__ __align__(16) f16 Bs[2 * BR * SA];

    const int tid = threadIdx.x;
    const int w = tid >> 6, l = tid & 63;
    const int wr = w >> 1, wc = w & 1;
    const int q = l >> 4, ln = l & 15;
    const int trow = tid / CPR, tch = tid % CPR;

    const int blk = blockIdx.x, xcd = blk & 7, local = blk >> 3;
    int up, rp;
    if constexpr (GRP == 0) { up = local & (NP - 1); rp = xcd * RPX + (local >> LNP); }
    else                    { up = xcd * NP + (local & (NP - 1)); rp = local >> LNP; }
    const int bu = up * BU, br = rp * BR;

    f32x4 acc[IM][IN];
#pragma unroll
    for (int a = 0; a < IM; ++a)
#pragma unroll
        for (int b = 0; b < IN; ++b)
            acc[a][b] = (f32x4){0.f, 0.f, 0.f, 0.f};

    const f16* Ab = A + (size_t)bu * KT;
    const f16* Bb = (MODE == 1) ? (const f16*)nullptr : B + (size_t)br * KT;

    f16x8 rA[PA], rB[PB], rC[(MODE == 1) ? PB : 1];

    auto load_stage = [&](int s) {
#pragma unroll
        for (int p = 0; p < PA; ++p)
            rA[p] = *(const f16x8*)(Ab + (size_t)(p * RPP + trow) * KT + s * BK + tch * 8);
        if constexpr (MODE == 1) {
#pragma unroll
            for (int p = 0; p < PB; ++p) {
                const size_t go = (size_t)(br + p * RPP + trow) * NF + s * BK + tch * 8;
                rB[p] = *(const f16x8*)(vb + go);
                rC[p] = *(const f16x8*)(cb + go);
            }
        } else {
#pragma unroll
            for (int p = 0; p < PB; ++p)
                rB[p] = *(const f16x8*)(Bb + (size_t)(p * RPP + trow) * KT + s * BK + tch * 8);
        }
    };
    auto write_stage = [&](int buf) {
        f16* Ad = As + buf * BU * SA + trow * SA + tch * 8;
        f16* Bd = Bs + buf * BR * SA + trow * SA + tch * 8;
#pragma unroll
        for (int p = 0; p < PA; ++p)
            *(f16x8*)(Ad + p * RPP * SA) = rA[p];
        if constexpr (MODE == 1) {
#pragma unroll
            for (int p = 0; p < PB; ++p) {
                f16x8 z;
#pragma unroll
                for (int e = 0; e < 8; ++e) z[e] = hclamp(rB[p][e], rC[p][e]);
                *(f16x8*)(Bd + p * RPP * SA) = z;
            }
        } else {
#pragma unroll
            for (int p = 0; p < PB; ++p)
                *(f16x8*)(Bd + p * RPP * SA) = rB[p];
        }
    };

    load_stage(0);
    write_stage(0);
    __syncthreads();

    for (int s = 0; s < NS; ++s) {
        if (s + 1 < NS) load_stage(s + 1);     // in flight during compute
        const f16* Ar = As + (s & 1) * BU * SA;
        const f16* Br = Bs + (s & 1) * BR * SA;
#pragma unroll
        for (int ks = 0; ks < BK / 32; ++ks) {
            f16x8 af[IM], bf[IN];
#pragma unroll
            for (int im = 0; im < IM; ++im)
                af[im] = *(const f16x8*)(Ar + (wr * WU + im * 16 + ln) * SA + ks * 32 + q * 8);
#pragma unroll
            for (int in = 0; in < IN; ++in)
                bf[in] = *(const f16x8*)(Br + (wc * WR + in * 16 + ln) * SA + ks * 32 + q * 8);
#pragma unroll
            for (int im = 0; im < IM; ++im)
#pragma unroll
                for (int in = 0; in < IN; ++in)
                    acc[im][in] = __builtin_amdgcn_mfma_f32_16x16x32_f16(
                        af[im], bf[in], acc[im][in], 0, 0, 0);
        }
        if (s + 1 < NS) write_stage((s + 1) & 1);   // vmcnt wait lands here
        __syncthreads();
    }

    // epilogue: C/D layout col(lane&15)=r-frag, row(q*4+reg)=u-frag (contig)
#pragma unroll
    for (int im = 0; im < IM; ++im) {
#pragma unroll
        for (int in = 0; in < IN; ++in) {
            const int u0 = bu + wr * WU + im * 16 + q * 4;
            const int r0 = br + wc * WR + in * 16 + ln;
            const size_t off = (size_t)r0 * ldo + u0;
            f32x4 a4 = acc[im][in];
            if constexpr (MODE == 0) {
                f16x4 cc, zz;
#pragma unroll
                for (int e = 0; e < 4; ++e) { cc[e] = (f16)(100.0f * a4[e]); zz[e] = (f16)0.0; }
                *(f16x4*)(o16 + off) = cc;
                *(f16x4*)(o16b + off) = zz;
            } else if constexpr (MODE == 1) {
                f16x4 yy;
#pragma unroll
                for (int e = 0; e < 4; ++e) yy[e] = (f16)a4[e];
                *(f16x4*)(o16 + off) = yy;
            } else if constexpr (MODE == 2 || MODE == 3) {
                f16x4 v4 = *(const f16x4*)(vb + off);
                f16x4 c4 = *(const f16x4*)(cb + off);
                f16x4 st;
#pragma unroll
                for (int e = 0; e < 4; ++e) {
                    f16 hz = hclamp(v4[e], c4[e]);            // == phase-1 operand
                    float vn = (float)v4[e] + 0.05f * (a4[e] - (float)hz);
                    if constexpr (MODE == 2) {
                        st[e] = (f16)vn;
                    } else {
                        float g = vn + (float)c4[e];          // F' = g - 0.05*h100
                        float zf = fminf(fmaxf(20.0f * g, -1.f), 1.f);
                        st[e] = (f16)(g - 0.05f * zf);
                    }
                }
                *(f16x4*)(o16 + off) = st;
            } else {
                f32x4 ov;
#pragma unroll
                for (int e = 0; e < 4; ++e) ov[e] = 0.01f * a4[e];
                *(f32x4*)(outF + off) = ov;
            }
        }
    }
}

extern "C" void kernel_launch(void* const* d_in, const int* in_sizes, int n_in,
                              void* d_out, int out_size, void* d_ws, size_t ws_size,
                              hipStream_t stream) {
    const float* x = (const float*)d_in[0];
    const int* idxs = (const int*)d_in[1];

    // Workspace: round-2's proven ~32.8 MB envelope.
    // Dg (8 MB) aliases Wg|Wh|BmY|c16-head — all dead before build_d runs.
    char* p = (char*)d_ws;
    auto take = [&](size_t n) { char* q = p; p += (n + 255) & ~(size_t)255; return q; };
    f16* Wg  = (f16*)take((size_t)MS * NF * 2);   // 2 MB
    f16* Wh  = (f16*)take((size_t)NF * MS * 2);   // 2 MB
    f16* BmY = (f16*)take((size_t)RS * MS * 2);   // 3 MB   Bm, then Y
    f16* c16 = (f16*)take((size_t)RS * NF * 2);   // 12.6 MB
    f16* v16 = (f16*)take((size_t)RS * NF * 2);   // 12.6 MB  v, then F'
    f16* Dg  = (f16*)d_ws;                        // aliased idct matrix

    build_w_kernel<<<dim3(MS * NF / 256), 256, 0, stream>>>(idxs, Wg, Wh);
    build_b_kernel<<<dim3(RS * MS / 256), 256, 0, stream>>>(x, idxs, BmY);

    // c = 100*Bm@A; v = 0   (tiles 128x128, K=512, 384 blocks)
    gemm_p<128, 128, 64, 512, 16, 3, 4, 0, 0><<<dim3(384), 256, 0, stream>>>(
        Wh, BmY, nullptr, nullptr, c16, v16, nullptr, NF);

    // 99 iterations
    for (int it = 0; it < 99; ++it) {
        // Y = Wg @ H(v,c)   (tiles 64x64, K=2048, 384 blocks)
        gemm_p<64, 64, 64, 2048, 8, 6, 3, 0, 1><<<dim3(384), 256, 0, stream>>>(
            Wg, nullptr, v16, c16, BmY, nullptr, nullptr, MS);
        // v += 0.05*(Wh@Y - H)   (tiles 128x64, K=512, 768 blocks)
        if (it < 98)
            gemm_p<128, 64, 64, 512, 16, 6, 4, 0, 2><<<dim3(768), 256, 0, stream>>>(
                Wh, BmY, v16, c16, v16, nullptr, nullptr, NF);
        else
            gemm_p<128, 64, 64, 512, 16, 6, 4, 0, 3><<<dim3(768), 256, 0, stream>>>(
                Wh, BmY, v16, c16, v16, nullptr, nullptr, NF);
    }

    // out = 0.01 * F' @ D   (tiles 128x128, K=2048, 384 blocks)
    build_d_kernel<<<dim3(NF * NF / 256), 256, 0, stream>>>(Dg);
    gemm_p<128, 128, 64, 2048, 2, 48, 1, 1, 4><<<dim3(384), 256, 0, stream>>>(
        Dg, v16, nullptr, nullptr, nullptr, nullptr, (float*)d_out, NF);
}